// Round 1
// 165.178 us; speedup vs baseline: 1.0095x; 1.0095x over previous
//
#include <hip/hip_runtime.h>
#include <math.h>

// Problem constants (from reference setup_inputs)
#define L0      3072
#define BATCH   1024
#define NNEG    512

// -------- workspace layout --------
// X0 : bf16[393216]            (feat @ w_self_0, bf16)
// Y0 : bf16[393216]            = X0 + 393216 elems
// H  : float @ 393216 (3072*512)   [A,B | C,D] layer-1 inputs
// R  : float @ 1966080 (3072*256)  layer-1 output, normalized
// spPos @ 2752512, spNeg @ 2752513, rank @ 2752514 (1024 ints), done @ rank+1024

__device__ __forceinline__ float bf2f(unsigned short u) {
  return __uint_as_float(((unsigned)u) << 16);
}
__device__ __forceinline__ void store_out(float v, float* p) { *p = v; }
__device__ __forceinline__ void store_out(float v, unsigned short* p) {
  unsigned x = __float_as_uint(v);                 // f32 -> bf16 RNE
  *p = (unsigned short)((x + 0x7fff + ((x >> 16) & 1)) >> 16);
}

// Half-split matmul, 6 rows x 256 cols per 512-thread block (grid 512,
// 2 blocks/CU = 16 waves/CU). Wave w: half=w>>2, colg=(w>>1)&1, rowg=w&1.
// Thread = 3 rows x 1 col. A-tile in LDS (broadcast ds_read_b128); W coalesced
// from global; unroll-4 lets the compiler software-pipeline.
// NORM: fused row L2-normalization (mm2 only).
template<int K, int AW, int HOFF, bool NORM, typename OutT>
__global__ __launch_bounds__(512) void k_mm(
    const float* __restrict__ Ain,
    const float* __restrict__ W0, const float* __restrict__ W1,
    OutT* __restrict__ Out, const int ldo, const int outHalfOff,
    float* __restrict__ zbuf, const int zcount) {
  __shared__ float AT[6 * AW];
  __shared__ float rs[8][3];
  const int t = threadIdx.x;
  if (zbuf != nullptr && blockIdx.x == 0)
    for (int z = t; z < zcount; z += 512) zbuf[z] = 0.f;
  const int base = blockIdx.x * 6;
  {
    const float4* __restrict__ src = (const float4*)(Ain + base * AW);
    float4* __restrict__ dst = (float4*)AT;
    for (int idx = t; idx < 6 * AW / 4; idx += 512) dst[idx] = src[idx];
  }
  __syncthreads();

  const int wave = t >> 6;
  const int half = wave >> 2;
  const int colg = (wave >> 1) & 1;
  const int rowg = wave & 1;
  const int rg = rowg * 3;
  const int col = colg * 64 + (t & 63);
  const float* __restrict__ W = (half ? W1 : W0) + col;
  const float* __restrict__ A0 = AT + rg * AW + half * HOFF;

  float acc[3] = {0.f, 0.f, 0.f};
#pragma unroll 4
  for (int d = 0; d < K; d += 4) {
    float4 a[3];
#pragma unroll
    for (int r = 0; r < 3; ++r) a[r] = *(const float4*)&A0[r * AW + d];
    float w[4];
#pragma unroll
    for (int i2 = 0; i2 < 4; ++i2) w[i2] = W[(d + i2) * 128];
#pragma unroll
    for (int i2 = 0; i2 < 4; ++i2)
#pragma unroll
      for (int r = 0; r < 3; ++r)
        acc[r] = fmaf(((const float*)&a[r])[i2], w[i2], acc[r]);
  }

  float scale[3] = {1.f, 1.f, 1.f};
  if (NORM) {
    float p[3];
#pragma unroll
    for (int r = 0; r < 3; ++r) p[r] = acc[r] * acc[r];
#pragma unroll
    for (int off = 32; off > 0; off >>= 1)
#pragma unroll
      for (int r = 0; r < 3; ++r) p[r] += __shfl_xor(p[r], off, 64);
    if ((t & 63) == 0) { rs[wave][0] = p[0]; rs[wave][1] = p[1]; rs[wave][2] = p[2]; }
    __syncthreads();
#pragma unroll
    for (int r = 0; r < 3; ++r) {
      const float s = rs[rowg][r] + rs[rowg + 2][r] + rs[rowg + 4][r] + rs[rowg + 6][r];
      scale[r] = rsqrtf(fmaxf(s, 1e-12f));
    }
  }
  OutT* __restrict__ O = Out + half * outHalfOff;
#pragma unroll
  for (int r = 0; r < 3; ++r)
    store_out(acc[r] * scale[r], &O[(base + rg + r) * ldo + col]);
}

// Fused layer-0 + layer-1 aggregation, bf16 gathers, ONE barrier.
// 640 threads = 10 waves; wave j owns hop-row j. (unchanged from R-best)
__global__ __launch_bounds__(640) void k_aggregate(
    const unsigned short* __restrict__ X0, const unsigned short* __restrict__ Y0,
    const int* __restrict__ nb0, const int* __restrict__ nb1,
    const int* __restrict__ nb2, float* __restrict__ H) {
  __shared__ float gB[10][128], gC[10][128], gD[10][128];
  const int i = blockIdx.x;
  const int t = threadIdx.x;
  const int n0 = nb0[i];                    // uniform s_load, in flight early
  const int j = t >> 6;                     // wave index = hop row j
  const int lam = t & 63;
  const int r = i * 10 + j;                 // wave-uniform
  int myidx = 0;
  if (lam < 25) myidx = nb2[r * 25 + lam];  // one coalesced 100B load/wave
  else if (lam == 25) myidx = nb1[r];
  const int c8 = lam & 15;
  const int sub = lam >> 4;

  float d8[8];
#pragma unroll
  for (int e = 0; e < 8; ++e) d8[e] = 0.f;
#pragma unroll
  for (int m = 0; m < 7; ++m) {
    const int k = sub + 4 * m;
    const int ridx = __shfl(myidx, k, 64);  // ds_bpermute distribute
    if (k < 25) {
      const float4 raw = *(const float4*)(Y0 + ridx * 128 + c8 * 8);  // 8 bf16
      const unsigned short* u = (const unsigned short*)&raw;
#pragma unroll
      for (int e = 0; e < 8; ++e) d8[e] += bf2f(u[e]);
    }
  }
#pragma unroll
  for (int e = 0; e < 8; ++e) d8[e] += __shfl_xor(d8[e], 16, 64);
#pragma unroll
  for (int e = 0; e < 8; ++e) d8[e] += __shfl_xor(d8[e], 32, 64);

  const int r1 = __shfl(myidx, 25, 64);
  if (sub == 0) {
#pragma unroll
    for (int e = 0; e < 8; ++e) gD[j][c8 * 8 + e] = fmaxf(d8[e] * 0.04f, 0.f);
    const float4 raw = *(const float4*)(Y0 + r1 * 128 + c8 * 8);
    const unsigned short* u = (const unsigned short*)&raw;
#pragma unroll
    for (int e = 0; e < 8; ++e) gB[j][c8 * 8 + e] = bf2f(u[e]);
  } else if (sub == 1) {
    const float4 raw = *(const float4*)(X0 + r1 * 128 + c8 * 8);
    const unsigned short* u = (const unsigned short*)&raw;
#pragma unroll
    for (int e = 0; e < 8; ++e) gC[j][c8 * 8 + e] = fmaxf(bf2f(u[e]), 0.f);
  }
  __syncthreads();

  if (t < 512) {
    const int q = t >> 7, c = t & 127;
    float v;
    if (q == 0) {
      v = fmaxf(bf2f(X0[n0 * 128 + c]), 0.f);
    } else {
      const float* g = (q == 1) ? &gB[0][0] : (q == 2) ? &gC[0][0] : &gD[0][0];
      float s = 0.f;
#pragma unroll
      for (int jj = 0; jj < 10; ++jj) s += g[jj * 128 + c];
      v = s * 0.1f;
      if (q == 1) v = fmaxf(v, 0.f);
    }
    H[i * 512 + t] = v;
  }
}

__device__ __forceinline__ float softplusf(float x) {
  return fmaxf(x, 0.f) + log1pf(expf(-fabsf(x)));
}

// neg_aff: 256 blocks (16 src rows x 128 neg cols) x 128 threads, per-thread
// 4x4 register tile over ds_read_b128 (stride 132 floats: 16B-aligned rows,
// 33-quad stride coprime with 8 quad-banks -> conflict-free; S/P reads are
// wave-broadcast). vs the old 128-block b32 version this cuts per-CU LDS
// issue ~3x AND uses all 256 CUs instead of 128.
// Tie semantics: pos rows are STAGED alongside neg rows; aff is computed by
// lanes t<16 with the IDENTICAL fmaf chain order (ch -> d4 -> i2, d ascending
// 0..255) as every acc chain, from the same staged f32 bits. Hence
// dot(S,P) == dot(S,N) bitwise whenever the pos and neg node ids coincide,
// reproducing the reference's stable positive-last ranking (rank = #(neg>=aff)).
// k_finalize is FUSED: threadfence + done-counter; 256th block computes
// mrr/loss via agent-scope atomic loads.
__global__ __launch_bounds__(128) void k_neg(
    const float* __restrict__ O, const int* __restrict__ src_idx,
    const int* __restrict__ pos_idx, const int* __restrict__ neg_idx,
    float* __restrict__ out_src, int* __restrict__ rank,
    float* __restrict__ spPos, float* __restrict__ spNeg,
    int* __restrict__ done) {
  __shared__ float lds[160 * 132];   // rows: [0,16) src, [16,32) pos, [32,160) neg
  __shared__ int rowIdx[160];
  __shared__ float affL[16];
  __shared__ int cntL[16];
  __shared__ float wsum[2];
  __shared__ int lastDone;
  const int t = threadIdx.x;
  const int rowBase = (blockIdx.x >> 2) * 16;
  const int colBase = (blockIdx.x & 3) * 128;
  const bool first = (colBase == 0);

  if (t < 16) { cntL[t] = 0; rowIdx[t] = src_idx[rowBase + t]; }
  else if (t < 32) rowIdx[t] = pos_idx[rowBase + t - 16];
  if (t >= 32) rowIdx[t] = neg_idx[colBase + t - 32];
  if (t < 32) rowIdx[128 + t] = neg_idx[colBase + 96 + t];

  if (first) {  // src_emb copy to d_out (16 rows x 64 float4)
    const float4* __restrict__ s4 = (const float4*)O;
    float4* __restrict__ d4o = (float4*)out_src;
#pragma unroll
    for (int idx = t; idx < 16 * 64; idx += 128) {
      const int rr = idx >> 6, c4 = idx & 63;
      d4o[(rowBase + rr) * 64 + c4] = s4[src_idx[rowBase + rr] * 64 + c4];
    }
  }
  __syncthreads();

  const int tc = t & 31;          // col group: cols {tc, tc+32, tc+64, tc+96}
  const int tr = t >> 5;          // row group: rows {tr, tr+4, tr+8, tr+12}
  float acc[4][4];
#pragma unroll
  for (int k = 0; k < 4; ++k)
#pragma unroll
    for (int j = 0; j < 4; ++j) acc[k][j] = 0.f;
  float aff = 0.f;

  for (int ch = 0; ch < 2; ++ch) {
    if (ch) __syncthreads();      // protect LDS reuse across halves
    {
      const float4* __restrict__ s4 = (const float4*)O;
#pragma unroll 4
      for (int idx = t; idx < 160 * 32; idx += 128) {
        const int row = idx >> 5, c4 = idx & 31;
        *(float4*)&lds[row * 132 + c4 * 4] = s4[rowIdx[row] * 64 + ch * 32 + c4];
      }
    }
    __syncthreads();
#pragma unroll 2
    for (int d4 = 0; d4 < 32; ++d4) {
      float4 a[4], b[4];
#pragma unroll
      for (int k = 0; k < 4; ++k)
        a[k] = *(const float4*)&lds[(tr + 4 * k) * 132 + d4 * 4];
#pragma unroll
      for (int j = 0; j < 4; ++j)
        b[j] = *(const float4*)&lds[(32 + tc + 32 * j) * 132 + d4 * 4];
      float4 sv, pv;
      if (t < 16) {
        sv = *(const float4*)&lds[t * 132 + d4 * 4];
        pv = *(const float4*)&lds[(16 + t) * 132 + d4 * 4];
      }
#pragma unroll
      for (int i2 = 0; i2 < 4; ++i2) {
#pragma unroll
        for (int k = 0; k < 4; ++k)
#pragma unroll
          for (int j = 0; j < 4; ++j)
            acc[k][j] = fmaf(((const float*)&a[k])[i2],
                             ((const float*)&b[j])[i2], acc[k][j]);
        if (t < 16)
          aff = fmaf(((const float*)&sv)[i2], ((const float*)&pv)[i2], aff);
      }
    }
  }
  if (t < 16) affL[t] = aff;
  __syncthreads();

  float sp = 0.f;
#pragma unroll
  for (int k = 0; k < 4; ++k) {
    const float av = affL[tr + 4 * k];
    int cnt = 0;
#pragma unroll
    for (int j = 0; j < 4; ++j) {
      const float v = acc[k][j];
      sp += softplusf(v);
      cnt += (v >= av) ? 1 : 0;
    }
    if (cnt) atomicAdd(&cntL[tr + 4 * k], cnt);
  }
#pragma unroll
  for (int off = 32; off > 0; off >>= 1) sp += __shfl_down(sp, off, 64);
  if ((t & 63) == 0) wsum[t >> 6] = sp;
  if (first && t < 16) atomicAdd(spPos, softplusf(-aff));
  __syncthreads();                 // cntL + wsum complete
  if (t == 0) atomicAdd(spNeg, wsum[0] + wsum[1]);
  if (t < 16) atomicAdd(&rank[rowBase + t], cntL[t]);

  // ---- fused finalize: last block computes mrr + loss ----
  __threadfence();
  __syncthreads();
  if (t == 0) lastDone = (atomicAdd(done, 1) == 255) ? 1 : 0;
  __syncthreads();
  if (lastDone) {
    float s = 0.f;
    for (int i = t; i < BATCH; i += 128) {
      const int rv = __hip_atomic_load(&rank[i], __ATOMIC_RELAXED,
                                       __HIP_MEMORY_SCOPE_AGENT);
      s += 1.f / (float)(rv + 1);
    }
#pragma unroll
    for (int off = 32; off > 0; off >>= 1) s += __shfl_down(s, off, 64);
    if ((t & 63) == 0) wsum[t >> 6] = s;
    __syncthreads();
    if (t == 0) {
      const float mrr = (wsum[0] + wsum[1]) * (1.f / 1024.f);
      const float p = __hip_atomic_load(spPos, __ATOMIC_RELAXED,
                                        __HIP_MEMORY_SCOPE_AGENT);
      const float n = __hip_atomic_load(spNeg, __ATOMIC_RELAXED,
                                        __HIP_MEMORY_SCOPE_AGENT);
      out_src[BATCH * 256]     = (p + n) * (1.f / 1024.f);
      out_src[BATCH * 256 + 1] = mrr;
    }
  }
}

extern "C" void kernel_launch(void* const* d_in, const int* in_sizes, int n_in,
                              void* d_out, int out_size, void* d_ws, size_t ws_size,
                              hipStream_t stream) {
  const float* feat   = (const float*)d_in[1];
  const int* src_idx  = (const int*)d_in[2];
  const int* pos_idx  = (const int*)d_in[3];
  const int* neg_idx  = (const int*)d_in[4];
  const int* nb0      = (const int*)d_in[5];
  const int* nb1      = (const int*)d_in[6];
  const int* nb2      = (const int*)d_in[7];
  const float* ws0    = (const float*)d_in[8];
  const float* wn0    = (const float*)d_in[9];
  const float* ws1    = (const float*)d_in[10];
  const float* wn1    = (const float*)d_in[11];

  float* wsf = (float*)d_ws;
  unsigned short* X0 = (unsigned short*)d_ws;       // bf16[393216]
  unsigned short* Y0 = X0 + 393216;                 // bf16[393216]
  float* H     = wsf + 393216;                      // 3072*512
  float* R     = wsf + 1966080;                     // 3072*256
  float* spPos = wsf + 2752512;
  float* spNeg = wsf + 2752513;
  int*   rank  = (int*)(wsf + 2752514);
  int*   done  = rank + 1024;
  float* out   = (float*)d_out;

  // X0 = bf16(feat@ws0), Y0 = bf16(feat@wn0); block 0 zeroes spPos/spNeg/rank/done
  k_mm<128, 128, 0, false, unsigned short><<<L0 / 6, 512, 0, stream>>>(
      feat, ws0, wn0, X0, 128, 393216, spPos, 1027);
  k_aggregate<<<L0, 640, 0, stream>>>(X0, Y0, nb0, nb1, nb2, H);
  // R[:, :128] = H[:, :256]@ws1 ; R[:, 128:] = H[:, 256:]@wn1 ; + L2-norm
  k_mm<256, 512, 256, true, float><<<L0 / 6, 512, 0, stream>>>(
      H, ws1, wn1, R, 256, 128, nullptr, 0);
  // 256 blocks = 64 row-tiles x 4 col-tiles; finalize fused (done-counter)
  k_neg<<<256, 128, 0, stream>>>(
      R, src_idx, pos_idx, neg_idx, out, rank, spPos, spNeg, done);
}